// Round 1
// baseline (542.380 us; speedup 1.0000x reference)
//
#include <hip/hip_runtime.h>

#define NL 21
#define NC 256
#define NB 64
#define PSTRIDE 72   // floats per LDS row: 18 float4; 72 % 32 = 8 -> <=2-way read conflicts (free)
#define PPB 16       // planes per block (consecutive c, same (feat,b) since 16|256)

// ---- persistent pipelined pooling kernel ----
// grid.x = 2*64*256/PPB = 2048 blocks; each handles PPB consecutive planes.
// Single LDS buffer (18.9 KB) -> 8 blocks/CU (32 waves = 100% occupancy).
// Register prefetch of plane i+1 overlaps compute(i); per-wave landmark
// shuffle-reduce replaces the serial row-sum + fold phases.
__global__ __launch_bounds__(256, 8) void pool_kernel(
    const float* __restrict__ f1, const float* __restrict__ f2,
    const float* __restrict__ pre1, const float* __restrict__ pre2,
    float* __restrict__ part1, float* __restrict__ part2) {
    const int p0   = blockIdx.x * PPB;       // first plane id
    const int feat = p0 >> 14;               // 16384 planes per feature
    const int b    = (p0 >> 8) & 63;
    const int c0   = p0 & 255;
    const float* __restrict__ base = (feat ? f2 : f1) + (size_t)(b * NC + c0) * 4096;
    const float* __restrict__ pre  = feat ? pre2 : pre1;
    float* __restrict__ outp       = (feat ? part2 : part1) + (size_t)b * NL * NC;

    __shared__ float buf[64 * PSTRIDE];
    __shared__ int s_left[NL], s_right[NL], s_down[NL], s_upper[NL];
    __shared__ float s_invs[NL];

    const int t    = threadIdx.x;
    const int wv   = t >> 6;                 // wave id 0..3
    const int lane = t & 63;
    const int rr   = lane >> 4;              // row-within-pass 0..3
    const int cc   = lane & 15;              // col offset 0..15 (need <12)

    // landmark bounds, once per block (faithful quirks: x -> H axis, y -> W axis;
    // trunc casts after clamp; inclusive divisor, exclusive sum)
    if (t < NL) {
        const float x = pre[(b * NL + t) * 2 + 0];
        const float y = pre[(b * NL + t) * 2 + 1];
        const int down  = (int)fmaxf(y - 6.0f, 0.0f);
        const int left  = (int)fmaxf(x - 6.0f, 0.0f);
        const int upper = (int)fminf(y + 6.0f, 63.0f);
        const int right = (int)fminf(x + 6.0f, 63.0f);
        s_left[t] = left; s_right[t] = right; s_down[t] = down; s_upper[t] = upper;
        s_invs[t] = 1.0f / (float)((upper - down + 1) * (right - left + 1));
    }

    // prologue: load plane 0 and stage it (float4 f -> row f>>4, col4 f&15)
    float4 v0, v1, v2, v3;
    {
        const float4* __restrict__ src = (const float4*)base;
        v0 = src[t]; v1 = src[t + 256]; v2 = src[t + 512]; v3 = src[t + 768];
        *(float4*)&buf[((t      ) >> 4) * PSTRIDE + ((t      ) & 15) * 4] = v0;
        *(float4*)&buf[((t + 256) >> 4) * PSTRIDE + ((t + 256) & 15) * 4] = v1;
        *(float4*)&buf[((t + 512) >> 4) * PSTRIDE + ((t + 512) & 15) * 4] = v2;
        *(float4*)&buf[((t + 768) >> 4) * PSTRIDE + ((t + 768) & 15) * 4] = v3;
    }
    __syncthreads();

    for (int i = 0; i < PPB; ++i) {
        // prefetch next plane into registers (vmcnt wait lands at the ds_write below)
        if (i + 1 < PPB) {
            const float4* __restrict__ src = (const float4*)(base + (size_t)(i + 1) * 4096);
            v0 = src[t]; v1 = src[t + 256]; v2 = src[t + 512]; v3 = src[t + 768];
        }
        // per-wave landmarks: wave wv handles l = wv, wv+4, ...
        for (int l = wv; l < NL; l += 4) {
            const int d = s_down[l], u = s_upper[l];
            const int L = s_left[l], R = s_right[l];
            const int col = d + cc;
            float s = 0.0f;
            if (col < u) {
                const float* __restrict__ rowp = &buf[col];
#pragma unroll
                for (int p = 0; p < 3; ++p) {
                    const int row = L + p * 4 + rr;   // p*4+rr covers 0..11
                    if (row < R) s += rowp[row * PSTRIDE];
                }
            }
#pragma unroll
            for (int o = 32; o > 0; o >>= 1) s += __shfl_xor(s, o, 64);
            if (lane == 0) outp[l * NC + (c0 + i)] = s * s_invs[l];
        }
        __syncthreads();   // all waves done reading buf
        if (i + 1 < PPB) {
            *(float4*)&buf[((t      ) >> 4) * PSTRIDE + ((t      ) & 15) * 4] = v0;
            *(float4*)&buf[((t + 256) >> 4) * PSTRIDE + ((t + 256) & 15) * 4] = v1;
            *(float4*)&buf[((t + 512) >> 4) * PSTRIDE + ((t + 512) & 15) * 4] = v2;
            *(float4*)&buf[((t + 768) >> 4) * PSTRIDE + ((t + 768) & 15) * 4] = v3;
        }
        __syncthreads();   // buf holds plane i+1
    }
}

// ---- reduce kernel: [64][21][256] -> [21][256] + EMA, per feature ----
// grid.x = 2*21 = 42 blocks, 256 threads
__global__ __launch_bounds__(256) void reduce_kernel(
    const float* __restrict__ part1, const float* __restrict__ part2,
    const float* __restrict__ fea1, const float* __restrict__ fea2,
    float* __restrict__ sc /* [2][21][256] */) {
    const int f = blockIdx.x / NL;
    const int l = blockIdx.x - f * NL;
    const int c = threadIdx.x;
    const float* __restrict__ part = f ? part2 : part1;
    const float* __restrict__ fea  = f ? fea2 : fea1;
    float s = 0.0f;
    for (int b = 0; b < NB; ++b) s += part[((size_t)b * NL + l) * NC + c];
    sc[(f * NL + l) * NC + c] = 0.999f * (s * (1.0f / 64.0f)) + 0.001f * fea[l * NC + c];
}

// ---- finish kernel: one wave per row, shuffle-only reductions ----
__global__ __launch_bounds__(256) void finish_kernel(const float* __restrict__ sc,
                                                     float* __restrict__ out) {
    const int t = threadIdx.x;
    const int wave = t >> 6, lane = t & 63;
    __shared__ float rowkl[NL];

    for (int l = wave; l < NL; l += 4) {
        const float* __restrict__ r1 = &sc[l * NC];            // fea_c1 row
        const float* __restrict__ r2 = &sc[(NL + l) * NC];     // fea_c2 row
        float x1[4], x2[4];
#pragma unroll
        for (int j = 0; j < 4; ++j) { x1[j] = r1[lane + 64 * j]; x2[j] = r2[lane + 64 * j]; }

        float m  = fmaxf(fmaxf(x1[0], x1[1]), fmaxf(x1[2], x1[3]));
        float s2 = x2[0] + x2[1] + x2[2] + x2[3];
#pragma unroll
        for (int o = 32; o > 0; o >>= 1) {
            m  = fmaxf(m, __shfl_xor(m, o, 64));
            s2 += __shfl_xor(s2, o, 64);
        }
        float es = 0.0f;
#pragma unroll
        for (int j = 0; j < 4; ++j) es += __expf(x1[j] - m);
#pragma unroll
        for (int o = 32; o > 0; o >>= 1) es += __shfl_xor(es, o, 64);
        const float logZ = m + logf(es);
        const float inv_s2 = 1.0f / s2;

        float kl = 0.0f;
#pragma unroll
        for (int j = 0; j < 4; ++j) {
            const float q = x2[j] * inv_s2;
            if (q > 0.0f) kl += q * (logf(q) - (x1[j] - logZ));
        }
#pragma unroll
        for (int o = 32; o > 0; o >>= 1) kl += __shfl_xor(kl, o, 64);
        if (lane == 0) rowkl[l] = kl;
    }
    __syncthreads();
    if (t == 0) {
        float tot = 0.0f;
        for (int l = 0; l < NL; ++l) tot += rowkl[l];
        out[0] = tot / 21.0f;
    }
}

extern "C" void kernel_launch(void* const* d_in, const int* in_sizes, int n_in,
                              void* d_out, int out_size, void* d_ws, size_t ws_size,
                              hipStream_t stream) {
    const float* f1   = (const float*)d_in[0];
    const float* f2   = (const float*)d_in[1];
    const float* pre1 = (const float*)d_in[2];
    const float* pre2 = (const float*)d_in[3];
    const float* fea1 = (const float*)d_in[4];
    const float* fea2 = (const float*)d_in[5];
    float* out = (float*)d_out;

    float* part1 = (float*)d_ws;                       // [64][21][256]
    float* part2 = part1 + (size_t)NB * NL * NC;       // [64][21][256]
    float* sc    = part2 + (size_t)NB * NL * NC;       // [2][21][256]

    pool_kernel<<<dim3(2 * NB * NC / PPB), 256, 0, stream>>>(f1, f2, pre1, pre2, part1, part2);
    reduce_kernel<<<dim3(2 * NL), 256, 0, stream>>>(part1, part2, fea1, fea2, sc);
    finish_kernel<<<1, 256, 0, stream>>>(sc, out);
}